// Round 1
// baseline (18601.942 us; speedup 1.0000x reference)
//
#include <hip/hip_runtime.h>
#include <hip/hip_bf16.h>

#define SEQ   512
#define BATCH 128
#define XD    256
#define PHID  512
#define RD    256
#define MUD   2048
#define OUTD  256
#define NBLK  32

typedef __attribute__((ext_vector_type(8))) short short8;
typedef __attribute__((ext_vector_type(4))) float floatx4;

__device__ inline short8 ld_frag(const __hip_bfloat16* p) {
    return *reinterpret_cast<const short8*>(p);
}

// Device-wide barrier: monotonically increasing epoch, agent-scope atomics +
// __threadfence for cross-XCD L2 visibility (per-XCD L2s are not coherent).
__device__ inline void gbar(int* cnt, int* gen, int epoch) {
    __syncthreads();
    if (threadIdx.x == 0) {
        __threadfence();  // release: flush this block's writes device-wide
        int prev = __hip_atomic_fetch_add(cnt, 1, __ATOMIC_RELAXED, __HIP_MEMORY_SCOPE_AGENT);
        if (prev == epoch * NBLK + (NBLK - 1)) {
            __hip_atomic_store(gen, epoch + 1, __ATOMIC_RELAXED, __HIP_MEMORY_SCOPE_AGENT);
        } else {
            while (__hip_atomic_load(gen, __ATOMIC_RELAXED, __HIP_MEMORY_SCOPE_AGENT) < epoch + 1) {
                __builtin_amdgcn_s_sleep(2);
            }
        }
        __threadfence();  // acquire: invalidate stale L1/L2 lines
    }
    __syncthreads();
}

// Pre-pass: fp32 -> bf16 conversions (x, W_mu2r, W_mu2o, W_xr2phi split x/r).
__global__ void convert_kernel(const float* __restrict__ x,
                               const float* __restrict__ w1,
                               const float* __restrict__ w2,
                               const float* __restrict__ wo,
                               __hip_bfloat16* __restrict__ xbf,
                               __hip_bfloat16* __restrict__ w1bf,
                               __hip_bfloat16* __restrict__ w2x,
                               __hip_bfloat16* __restrict__ w2r,
                               __hip_bfloat16* __restrict__ wobf)
{
    const int stride = gridDim.x * blockDim.x;
    const int gid = blockIdx.x * blockDim.x + threadIdx.x;
    for (int i = gid; i < SEQ * BATCH * XD; i += stride) xbf[i] = __float2bfloat16(x[i]);
    for (int i = gid; i < RD * MUD; i += stride)         w1bf[i] = __float2bfloat16(w1[i]);
    for (int i = gid; i < OUTD * MUD; i += stride)       wobf[i] = __float2bfloat16(wo[i]);
    for (int i = gid; i < PHID * XD; i += stride) {
        int n = i >> 8, k = i & 255;
        w2x[i] = __float2bfloat16(w2[n * (XD + RD) + k]);
        w2r[i] = __float2bfloat16(w2[n * (XD + RD) + XD + k]);
    }
}

// Persistent scan kernel. 32 blocks x 256 threads (4 waves), all co-resident.
// Phase A (blocks 0..15): r = relu(mu_bf16 @ W1^T + b1)          [M=128,N=256,K=2048]
// Phase B (all 32):       phi tile + in-place 4-alpha EMA on mu  [M=128,N=512,K=512]
// MFMA 16x16x32 bf16; A-frag: A[m=lane&15][k=8*quad+j]; B-frag: B[k][n=lane&15];
// C/D: row=(quad*4+i), col=lane&15.
__global__ void __launch_bounds__(256) sru_scan(
    float* __restrict__ mu, __hip_bfloat16* __restrict__ mubf,
    __hip_bfloat16* __restrict__ rbf,
    const __hip_bfloat16* __restrict__ xbf,
    const __hip_bfloat16* __restrict__ w1bf,
    const __hip_bfloat16* __restrict__ w2x,
    const __hip_bfloat16* __restrict__ w2r,
    const __hip_bfloat16* __restrict__ wobf,
    const float* __restrict__ b1, const float* __restrict__ b2,
    const float* __restrict__ bo,
    float* __restrict__ out, int* __restrict__ ctrl)
{
    const int bid  = blockIdx.x;
    const int tid  = threadIdx.x;
    const int wave = tid >> 6;
    const int lane = tid & 63;
    const int quad = lane >> 4;
    const int lrow = lane & 15;
    const int m0   = wave * 32;   // each wave owns 32 batch rows (2 m-tiles)
    int* cnt = ctrl;
    int* gen = ctrl + 1;
    int epoch = 0;

    #pragma unroll 1
    for (int t = 0; t < SEQ; ++t) {
        // ---- Phase A: r = relu(mu @ W_mu2r^T + b1) ----
        if (bid < 16) {
            const int j0 = bid * 16;
            floatx4 acc0 = {0.f, 0.f, 0.f, 0.f};
            floatx4 acc1 = {0.f, 0.f, 0.f, 0.f};
            const __hip_bfloat16* Ar0 = mubf + (m0 + lrow) * MUD;
            const __hip_bfloat16* Ar1 = mubf + (m0 + 16 + lrow) * MUD;
            const __hip_bfloat16* Br  = w1bf + (j0 + lrow) * MUD;
            #pragma unroll 8
            for (int k = 0; k < MUD; k += 32) {
                const int ko = k + 8 * quad;
                short8 a0 = ld_frag(Ar0 + ko);
                short8 a1 = ld_frag(Ar1 + ko);
                short8 b  = ld_frag(Br + ko);
                acc0 = __builtin_amdgcn_mfma_f32_16x16x32_bf16(a0, b, acc0, 0, 0, 0);
                acc1 = __builtin_amdgcn_mfma_f32_16x16x32_bf16(a1, b, acc1, 0, 0, 0);
            }
            const float bj = b1[j0 + lrow];
            #pragma unroll
            for (int i = 0; i < 4; ++i) {
                const int r0 = m0 + quad * 4 + i;
                const int r1 = r0 + 16;
                rbf[r0 * RD + j0 + lrow] = __float2bfloat16(fmaxf(acc0[i] + bj, 0.f));
                rbf[r1 * RD + j0 + lrow] = __float2bfloat16(fmaxf(acc1[i] + bj, 0.f));
            }
        }
        gbar(cnt, gen, epoch); ++epoch;

        // ---- Phase B: phi tile + mu EMA update ----
        {
            const int j0 = bid * 16;
            floatx4 acc0 = {0.f, 0.f, 0.f, 0.f};
            floatx4 acc1 = {0.f, 0.f, 0.f, 0.f};
            const __hip_bfloat16* xt  = xbf + (size_t)t * BATCH * XD;
            const __hip_bfloat16* Brx = w2x + (j0 + lrow) * XD;
            #pragma unroll 8
            for (int k = 0; k < XD; k += 32) {
                const int ko = k + 8 * quad;
                short8 a0 = ld_frag(xt + (m0 + lrow) * XD + ko);
                short8 a1 = ld_frag(xt + (m0 + 16 + lrow) * XD + ko);
                short8 b  = ld_frag(Brx + ko);
                acc0 = __builtin_amdgcn_mfma_f32_16x16x32_bf16(a0, b, acc0, 0, 0, 0);
                acc1 = __builtin_amdgcn_mfma_f32_16x16x32_bf16(a1, b, acc1, 0, 0, 0);
            }
            const __hip_bfloat16* Brr = w2r + (j0 + lrow) * RD;
            #pragma unroll 8
            for (int k = 0; k < RD; k += 32) {
                const int ko = k + 8 * quad;
                short8 a0 = ld_frag(rbf + (m0 + lrow) * RD + ko);
                short8 a1 = ld_frag(rbf + (m0 + 16 + lrow) * RD + ko);
                short8 b  = ld_frag(Brr + ko);
                acc0 = __builtin_amdgcn_mfma_f32_16x16x32_bf16(a0, b, acc0, 0, 0, 0);
                acc1 = __builtin_amdgcn_mfma_f32_16x16x32_bf16(a1, b, acc1, 0, 0, 0);
            }
            const float bj = b2[j0 + lrow];
            const float alphas[4] = {0.0f, 0.5f, 0.9f, 0.99f};
            #pragma unroll
            for (int half = 0; half < 2; ++half) {
                #pragma unroll
                for (int i = 0; i < 4; ++i) {
                    const int row = m0 + 16 * half + quad * 4 + i;
                    const float ph = fmaxf((half ? acc1[i] : acc0[i]) + bj, 0.f);
                    #pragma unroll
                    for (int a = 0; a < 4; ++a) {
                        const int idx = row * MUD + a * PHID + j0 + lrow;
                        const float mn = alphas[a] * mu[idx] + (1.f - alphas[a]) * ph;
                        mu[idx]   = mn;
                        mubf[idx] = __float2bfloat16(mn);
                    }
                }
            }
        }
        gbar(cnt, gen, epoch); ++epoch;
    }

    // ---- Final: out = relu(mu @ W_mu2o^T + bo) ----
    if (bid < 16) {
        const int j0 = bid * 16;
        floatx4 acc0 = {0.f, 0.f, 0.f, 0.f};
        floatx4 acc1 = {0.f, 0.f, 0.f, 0.f};
        const __hip_bfloat16* Ar0 = mubf + (m0 + lrow) * MUD;
        const __hip_bfloat16* Ar1 = mubf + (m0 + 16 + lrow) * MUD;
        const __hip_bfloat16* Br  = wobf + (j0 + lrow) * MUD;
        #pragma unroll 8
        for (int k = 0; k < MUD; k += 32) {
            const int ko = k + 8 * quad;
            short8 a0 = ld_frag(Ar0 + ko);
            short8 a1 = ld_frag(Ar1 + ko);
            short8 b  = ld_frag(Br + ko);
            acc0 = __builtin_amdgcn_mfma_f32_16x16x32_bf16(a0, b, acc0, 0, 0, 0);
            acc1 = __builtin_amdgcn_mfma_f32_16x16x32_bf16(a1, b, acc1, 0, 0, 0);
        }
        const float bj = bo[j0 + lrow];
        #pragma unroll
        for (int i = 0; i < 4; ++i) {
            const int r0 = m0 + quad * 4 + i;
            const int r1 = r0 + 16;
            out[r0 * OUTD + j0 + lrow] = fmaxf(acc0[i] + bj, 0.f);
            out[r1 * OUTD + j0 + lrow] = fmaxf(acc1[i] + bj, 0.f);
        }
    }
}

extern "C" void kernel_launch(void* const* d_in, const int* in_sizes, int n_in,
                              void* d_out, int out_size, void* d_ws, size_t ws_size,
                              hipStream_t stream)
{
    const float* x  = (const float*)d_in[0];
    const float* w1 = (const float*)d_in[1];
    const float* b1 = (const float*)d_in[2];
    const float* w2 = (const float*)d_in[3];
    const float* b2 = (const float*)d_in[4];
    const float* wo = (const float*)d_in[5];
    const float* bo = (const float*)d_in[6];
    float* out = (float*)d_out;
    char* ws = (char*)d_ws;

    constexpr size_t O_CTRL = 0;
    constexpr size_t O_MU   = 64;
    constexpr size_t O_MUBF = O_MU + (size_t)BATCH * MUD * 4;
    constexpr size_t ZERO_BYTES = O_MUBF + (size_t)BATCH * MUD * 2;  // ctrl + mu + mubf
    constexpr size_t O_RBF  = ZERO_BYTES;
    constexpr size_t O_X    = O_RBF + (size_t)BATCH * RD * 2;
    constexpr size_t O_W1   = O_X + (size_t)SEQ * BATCH * XD * 2;
    constexpr size_t O_W2X  = O_W1 + (size_t)RD * MUD * 2;
    constexpr size_t O_W2R  = O_W2X + (size_t)PHID * XD * 2;
    constexpr size_t O_WO   = O_W2R + (size_t)PHID * XD * 2;

    hipMemsetAsync(ws + O_CTRL, 0, ZERO_BYTES, stream);

    convert_kernel<<<2048, 256, 0, stream>>>(
        x, w1, w2, wo,
        (__hip_bfloat16*)(ws + O_X), (__hip_bfloat16*)(ws + O_W1),
        (__hip_bfloat16*)(ws + O_W2X), (__hip_bfloat16*)(ws + O_W2R),
        (__hip_bfloat16*)(ws + O_WO));

    sru_scan<<<NBLK, 256, 0, stream>>>(
        (float*)(ws + O_MU), (__hip_bfloat16*)(ws + O_MUBF),
        (__hip_bfloat16*)(ws + O_RBF),
        (const __hip_bfloat16*)(ws + O_X),
        (const __hip_bfloat16*)(ws + O_W1),
        (const __hip_bfloat16*)(ws + O_W2X),
        (const __hip_bfloat16*)(ws + O_W2R),
        (const __hip_bfloat16*)(ws + O_WO),
        b1, b2, bo, out, (int*)(ws + O_CTRL));
}

// Round 2
// 5511.851 us; speedup vs baseline: 3.3749x; 3.3749x over previous
//
#include <hip/hip_runtime.h>
#include <hip/hip_bf16.h>

#define SEQ   512
#define BATCH 128
#define XD    256
#define PHID  512
#define RD    256
#define OUTD  256
#define NBLK  48

typedef __attribute__((ext_vector_type(8))) short short8;
typedef __attribute__((ext_vector_type(4))) float floatx4;

#define MFMA(a, b, c) __builtin_amdgcn_mfma_f32_16x16x32_bf16((a), (b), (c), 0, 0, 0)

__device__ inline short8 ldg8(const __hip_bfloat16* p) {
    return *reinterpret_cast<const short8*>(p);
}
__device__ inline int flagld(const int* p) {
    return __hip_atomic_load(p, __ATOMIC_RELAXED, __HIP_MEMORY_SCOPE_AGENT);
}
__device__ inline void flagst(int* p, int v) {
    __hip_atomic_store(p, v, __ATOMIC_RELAXED, __HIP_MEMORY_SCOPE_AGENT);
}

__global__ void convert_x(const float* __restrict__ x, __hip_bfloat16* __restrict__ xbf) {
    const int gid = blockIdx.x * blockDim.x + threadIdx.x;   // grid covers N/4 exactly
    const float4 v = reinterpret_cast<const float4*>(x)[gid];
    __hip_bfloat16* d = xbf + 4 * (size_t)gid;
    d[0] = __float2bfloat16(v.x); d[1] = __float2bfloat16(v.y);
    d[2] = __float2bfloat16(v.z); d[3] = __float2bfloat16(v.w);
}

// 48 persistent blocks:
//   bid  0..15 : phi-blocks  — 32 cols of phi each; x-part GEMM overlaps the r-wait
//   bid 16..31 : s-blocks    — 16 cols of r; keep s_a = mu_a @ W1_a^T in regs (4 alphas)
//   bid 32..47 : o-blocks    — 16 cols of out; keep o_a = mu_a @ Wo_a^T in regs (lag freely)
// Epoch flags (monotone, memset 0 per call): rfl/pfl/ofl, one per producer block.
// LDS weight layout [slab][k/8][n][8] -> ds_read_b128 fragments, even 8-cyc banking, no pad.
__global__ void __launch_bounds__(256) sru_pipe(
    const float* __restrict__ W1, const float* __restrict__ W2,
    const float* __restrict__ Wo,
    const float* __restrict__ b1, const float* __restrict__ b2,
    const float* __restrict__ bo,
    const __hip_bfloat16* __restrict__ xbf,
    __hip_bfloat16* __restrict__ rbf,
    __hip_bfloat16* __restrict__ phib,
    float* __restrict__ out, int* __restrict__ ctrl)
{
    __shared__ __hip_bfloat16 wlds[32768];   // 64 KB
    const int bid  = blockIdx.x;
    const int tid  = threadIdx.x;
    const int wave = tid >> 6;
    const int lane = tid & 63;
    const int quad = lane >> 4;
    const int lrow = lane & 15;
    const int m0   = wave * 32;              // each wave owns 32 batch rows
    int* rfl = ctrl;
    int* pfl = ctrl + 256;
    int* ofl = ctrl + 512;

    if (bid < 16) {
        // ================= phi-block =================
        const int j0 = bid * 32;
        for (int i = tid * 4; i < 2 * 32 * 256; i += 1024) {
            const int part = i >> 13, rem = i & 8191;
            const int n = rem >> 8, k = rem & 255;
            const float4 v = *reinterpret_cast<const float4*>(
                &W2[(j0 + n) * (XD + RD) + part * 256 + k]);
            __hip_bfloat16* dst = &wlds[(((part * 32 + (k >> 3)) * 32 + n) << 3) + (k & 7)];
            dst[0] = __float2bfloat16(v.x); dst[1] = __float2bfloat16(v.y);
            dst[2] = __float2bfloat16(v.z); dst[3] = __float2bfloat16(v.w);
        }
        __syncthreads();
        const float bj0 = b2[j0 + lrow];
        const float bj1 = b2[j0 + 16 + lrow];
        #pragma unroll 1
        for (int t = 0; t < SEQ; ++t) {
            floatx4 acc[2][2] = {};
            // x-part (no dependency on this step's r) — overlaps the r-wait below
            const __hip_bfloat16* xt = xbf + (size_t)(t * BATCH + m0) * XD;
            #pragma unroll
            for (int k = 0; k < XD; k += 32) {
                const short8 a0 = ldg8(xt + lrow * XD + k + 8 * quad);
                const short8 a1 = ldg8(xt + (16 + lrow) * XD + k + 8 * quad);
                #pragma unroll
                for (int j2 = 0; j2 < 2; ++j2) {
                    const short8 b = *reinterpret_cast<const short8*>(
                        &wlds[((((k >> 3) + quad) * 32 + j2 * 16 + lrow) << 3)]);
                    acc[0][j2] = MFMA(a0, b, acc[0][j2]);
                    acc[1][j2] = MFMA(a1, b, acc[1][j2]);
                }
            }
            // wait r_t (16 s-flags) and gate phi ring slot on o-progress
            if (tid < 16) {
                while (flagld(&rfl[tid * 16]) < t + 1) __builtin_amdgcn_s_sleep(2);
            } else if (tid < 32) {
                const int g = t - 3;
                while (flagld(&ofl[(tid - 16) * 16]) < g) __builtin_amdgcn_s_sleep(2);
            }
            __syncthreads();
            if (tid == 0) __threadfence();   // acquire: see s-blocks' r stores
            __syncthreads();
            // r-part
            #pragma unroll
            for (int k = 0; k < RD; k += 32) {
                const short8 a0 = ldg8(rbf + (m0 + lrow) * RD + k + 8 * quad);
                const short8 a1 = ldg8(rbf + (m0 + 16 + lrow) * RD + k + 8 * quad);
                #pragma unroll
                for (int j2 = 0; j2 < 2; ++j2) {
                    const short8 b = *reinterpret_cast<const short8*>(
                        &wlds[(((32 + (k >> 3) + quad) * 32 + j2 * 16 + lrow) << 3)]);
                    acc[0][j2] = MFMA(a0, b, acc[0][j2]);
                    acc[1][j2] = MFMA(a1, b, acc[1][j2]);
                }
            }
            __hip_bfloat16* pb = phib + (size_t)(t & 3) * BATCH * PHID;
            #pragma unroll
            for (int h = 0; h < 2; ++h)
                #pragma unroll
                for (int j2 = 0; j2 < 2; ++j2)
                    #pragma unroll
                    for (int i = 0; i < 4; ++i) {
                        const int row = m0 + 16 * h + quad * 4 + i;
                        const float v = (h ? acc[1][j2][i] : acc[0][j2][i]) + (j2 ? bj1 : bj0);
                        pb[row * PHID + j0 + j2 * 16 + lrow] = __float2bfloat16(fmaxf(v, 0.f));
                    }
            __syncthreads();                 // drain all waves' phi stores to L2
            if (tid == 0) { __threadfence(); flagst(&pfl[bid * 16], t + 1); }
        }
    } else if (bid < 32) {
        // ================= s-block =================
        const int sb = bid - 16, j0 = sb * 16;
        for (int i = tid * 4; i < 4 * 16 * 512; i += 1024) {
            const int a = i >> 13, rem = i & 8191;
            const int n = rem >> 9, k = rem & 511;
            const float4 v = *reinterpret_cast<const float4*>(
                &W1[(j0 + n) * 2048 + a * 512 + k]);
            __hip_bfloat16* dst = &wlds[(((a * 64 + (k >> 3)) * 16 + n) << 3) + (k & 7)];
            dst[0] = __float2bfloat16(v.x); dst[1] = __float2bfloat16(v.y);
            dst[2] = __float2bfloat16(v.z); dst[3] = __float2bfloat16(v.w);
        }
        __syncthreads();
        const float bjv = b1[j0 + lrow];
        const float pre[4]  = {0.f, 1.f, 9.f, 99.f};    // alpha/(1-alpha)
        const float post[4] = {1.f, 0.5f, 0.1f, 0.01f}; // (1-alpha)
        floatx4 s[4][2] = {};
        #pragma unroll 1
        for (int t = 0; t < SEQ; ++t) {
            // emit r_t = relu(sum_a s_a + b1)
            #pragma unroll
            for (int h = 0; h < 2; ++h)
                #pragma unroll
                for (int i = 0; i < 4; ++i) {
                    const int row = m0 + 16 * h + quad * 4 + i;
                    const float rv = s[0][h][i] + s[1][h][i] + s[2][h][i] + s[3][h][i] + bjv;
                    rbf[row * RD + j0 + lrow] = __float2bfloat16(fmaxf(rv, 0.f));
                }
            __syncthreads();
            if (tid == 0) { __threadfence(); flagst(&rfl[sb * 16], t + 1); }
            if (t == SEQ - 1) break;
            // wait phi_t
            if (tid < 16) {
                while (flagld(&pfl[tid * 16]) < t + 1) __builtin_amdgcn_s_sleep(2);
            }
            __syncthreads();
            if (tid == 0) __threadfence();
            __syncthreads();
            #pragma unroll
            for (int a = 0; a < 4; ++a)
                #pragma unroll
                for (int h = 0; h < 2; ++h)
                    s[a][h] *= pre[a];
            const __hip_bfloat16* pb = phib + (size_t)(t & 3) * BATCH * PHID;
            #pragma unroll 8
            for (int k = 0; k < PHID; k += 32) {
                const short8 a0 = ldg8(pb + (m0 + lrow) * PHID + k + 8 * quad);
                const short8 a1 = ldg8(pb + (m0 + 16 + lrow) * PHID + k + 8 * quad);
                #pragma unroll
                for (int a = 0; a < 4; ++a) {
                    const short8 b = *reinterpret_cast<const short8*>(
                        &wlds[(((a * 64 + (k >> 3) + quad) * 16 + lrow) << 3)]);
                    s[a][0] = MFMA(a0, b, s[a][0]);
                    s[a][1] = MFMA(a1, b, s[a][1]);
                }
            }
            #pragma unroll
            for (int a = 0; a < 4; ++a)
                #pragma unroll
                for (int h = 0; h < 2; ++h)
                    s[a][h] *= post[a];
        }
    } else {
        // ================= o-block =================
        const int ob = bid - 32, j0 = ob * 16;
        for (int i = tid * 4; i < 4 * 16 * 512; i += 1024) {
            const int a = i >> 13, rem = i & 8191;
            const int n = rem >> 9, k = rem & 511;
            const float4 v = *reinterpret_cast<const float4*>(
                &Wo[(j0 + n) * 2048 + a * 512 + k]);
            __hip_bfloat16* dst = &wlds[(((a * 64 + (k >> 3)) * 16 + n) << 3) + (k & 7)];
            dst[0] = __float2bfloat16(v.x); dst[1] = __float2bfloat16(v.y);
            dst[2] = __float2bfloat16(v.z); dst[3] = __float2bfloat16(v.w);
        }
        __syncthreads();
        const float pre[4]  = {0.f, 1.f, 9.f, 99.f};
        const float post[4] = {1.f, 0.5f, 0.1f, 0.01f};
        floatx4 o[4][2] = {};
        #pragma unroll 1
        for (int t = 0; t < SEQ; ++t) {
            if (tid < 16) {
                while (flagld(&pfl[tid * 16]) < t + 1) __builtin_amdgcn_s_sleep(2);
            }
            __syncthreads();
            if (tid == 0) __threadfence();
            __syncthreads();
            #pragma unroll
            for (int a = 0; a < 4; ++a)
                #pragma unroll
                for (int h = 0; h < 2; ++h)
                    o[a][h] *= pre[a];
            const __hip_bfloat16* pb = phib + (size_t)(t & 3) * BATCH * PHID;
            #pragma unroll 8
            for (int k = 0; k < PHID; k += 32) {
                const short8 a0 = ldg8(pb + (m0 + lrow) * PHID + k + 8 * quad);
                const short8 a1 = ldg8(pb + (m0 + 16 + lrow) * PHID + k + 8 * quad);
                #pragma unroll
                for (int a = 0; a < 4; ++a) {
                    const short8 b = *reinterpret_cast<const short8*>(
                        &wlds[(((a * 64 + (k >> 3) + quad) * 16 + lrow) << 3)]);
                    o[a][0] = MFMA(a0, b, o[a][0]);
                    o[a][1] = MFMA(a1, b, o[a][1]);
                }
            }
            #pragma unroll
            for (int a = 0; a < 4; ++a)
                #pragma unroll
                for (int h = 0; h < 2; ++h)
                    o[a][h] *= post[a];
            __syncthreads();                  // phi reads drained
            if (tid == 0) flagst(&ofl[ob * 16], t + 1);
        }
        const float bjo = bo[j0 + lrow];
        #pragma unroll
        for (int h = 0; h < 2; ++h)
            #pragma unroll
            for (int i = 0; i < 4; ++i) {
                const int row = m0 + 16 * h + quad * 4 + i;
                const float v = o[0][h][i] + o[1][h][i] + o[2][h][i] + o[3][h][i] + bjo;
                out[row * OUTD + j0 + lrow] = fmaxf(v, 0.f);
            }
    }
}

extern "C" void kernel_launch(void* const* d_in, const int* in_sizes, int n_in,
                              void* d_out, int out_size, void* d_ws, size_t ws_size,
                              hipStream_t stream)
{
    const float* x  = (const float*)d_in[0];
    const float* W1 = (const float*)d_in[1];
    const float* b1 = (const float*)d_in[2];
    const float* W2 = (const float*)d_in[3];
    const float* b2 = (const float*)d_in[4];
    const float* Wo = (const float*)d_in[5];
    const float* bo = (const float*)d_in[6];
    float* out = (float*)d_out;
    char* ws = (char*)d_ws;

    constexpr size_t O_CTRL = 0;                                 // 768 ints, 64B-spaced flags
    constexpr size_t O_RBF  = 4096;                              // 128x256 bf16 = 64 KB
    constexpr size_t O_PHI  = O_RBF + (size_t)BATCH * RD * 2;    // 4 x 128x512 bf16 = 512 KB
    constexpr size_t O_X    = O_PHI + 4ull * BATCH * PHID * 2;   // 512x128x256 bf16 = 32 MB

    hipMemsetAsync(ws + O_CTRL, 0, 3072, stream);
    convert_x<<<SEQ * BATCH * XD / 4 / 256, 256, 0, stream>>>(
        x, (__hip_bfloat16*)(ws + O_X));
    sru_pipe<<<NBLK, 256, 0, stream>>>(
        W1, W2, Wo, b1, b2, bo,
        (const __hip_bfloat16*)(ws + O_X),
        (__hip_bfloat16*)(ws + O_RBF),
        (__hip_bfloat16*)(ws + O_PHI),
        out, (int*)(ws + O_CTRL));
}